// Round 7
// baseline (234.290 us; speedup 1.0000x reference)
//
#include <hip/hip_runtime.h>
#include <hip/hip_bf16.h>

// PoolAggregator: out[b,h] = mean_s relu( W @ features[idx[b,s]] + bias )
// B=10000, S=32, N=100000, D_IN=512, D_H=512.
//
// Pipeline (ws >= 103 MB):
//   0) cvt_bf16: W f32 -> Wb bf16 (0.5 MB) only.
//   1) gemm_hf3: H = relu(feat @ Wb^T + b) -> bf16, fused f32->bf16 for A.
//      T4 schedule: raw s_barrier + counted s_waitcnt vmcnt(12) -- A-prefetch
//      and next-W global_load_lds stay in flight ACROSS barriers (never drain
//      to 0 in the main loop). A(ki+1) issued at end of step ki-1 (1 full
//      K-step of latency cover). LDS 48KB (As single + Bs dbuf), 3 blocks/CU.
//   2) pool_mean4: out[b,:] = mean_s H[idx[b,s],:].
// Fallbacks: ws >= 102.4 MB -> f32-reg-staged gemm; else fused gather GEMM.

#define S_NB 32
#define D_IN 512
#define D_H  512
#define BM   128
#define BN   128
#define BK   64
#define NK   (D_IN / BK)            // 8
#define NNODE 100000
#define NBATCH 10000
#define NTILE_N 4
#define NTILE_M 784                 // padded so NTILES = 8 * 392, 392 % 4 == 0
#define NTILES  (NTILE_N * NTILE_M) // 3136

typedef __attribute__((ext_vector_type(8))) short  short8;
typedef __attribute__((ext_vector_type(4))) float  f32x4;
typedef __attribute__((ext_vector_type(4))) unsigned short us4;
typedef __attribute__((ext_vector_type(8))) unsigned short us8;

#define WAITVM12() asm volatile("s_waitcnt vmcnt(12)" ::: "memory")
#define WAITVM0()  asm volatile("s_waitcnt vmcnt(0)" ::: "memory")
#define WAITLGKM0() asm volatile("s_waitcnt lgkmcnt(0)" ::: "memory")
#define SBAR()   __builtin_amdgcn_s_barrier()
#define SCHED0() __builtin_amdgcn_sched_barrier(0)

__device__ __forceinline__ unsigned short f2bf(float x) {
  union { float f; unsigned u; } v; v.f = x;
  unsigned r = v.u + 0x7FFFu + ((v.u >> 16) & 1u);
  return (unsigned short)(r >> 16);
}

__device__ __forceinline__ float bf2f(unsigned short x) {
  union { unsigned u; float f; } v; v.u = ((unsigned)x) << 16;
  return v.f;
}

// byte offset into a [128][64]-bf16 LDS tile (row stride 128B) with XOR swizzle
__device__ __forceinline__ int swz(int row, int cb) {
  return row * 128 + (cb ^ ((row & 7) << 4));
}

// async global->LDS, 16B/lane
__device__ __forceinline__ void gld_lds16(const unsigned short* g, unsigned short* l) {
  __builtin_amdgcn_global_load_lds(
      (const __attribute__((address_space(1))) unsigned int*)g,
      (__attribute__((address_space(3))) unsigned int*)l, 16, 0, 0);
}

// ---------------- Phase 0: f32 -> bf16 (W only in primary path) ----------------
__global__ __launch_bounds__(256, 8)
void cvt_bf16(const float* __restrict__ src, unsigned short* __restrict__ dst, int n8) {
  int i = blockIdx.x * blockDim.x + threadIdx.x;
  const int stride = gridDim.x * blockDim.x;
  for (; i < n8; i += stride) {
    f32x4 a = *(const f32x4*)(src + (size_t)i * 8);
    f32x4 b = *(const f32x4*)(src + (size_t)i * 8 + 4);
    us8 o;
    o[0] = f2bf(a.x); o[1] = f2bf(a.y); o[2] = f2bf(a.z); o[3] = f2bf(a.w);
    o[4] = f2bf(b.x); o[5] = f2bf(b.y); o[6] = f2bf(b.z); o[7] = f2bf(b.w);
    *(us8*)(dst + (size_t)i * 8) = o;
  }
}

// ---------------- Phase 1: H = relu(feat @ Wb^T + b) -> bf16, fused cvt, T4 ----------------
__global__ __launch_bounds__(256, 3)
void gemm_hf3(const float* __restrict__ feat,
              const unsigned short* __restrict__ Wb,
              const float* __restrict__ bias,
              unsigned short* __restrict__ Hb) {
  const int tid  = threadIdx.x;
  const int lane = tid & 63;
  const int wid  = tid >> 6;
  const int wr   = wid >> 1;
  const int wc   = wid & 1;

  // XCD-chunked swizzle: XCD k (bid%8) gets 392 sequential tiles, n-tile fastest.
  const int bid  = blockIdx.x;
  const int tile = (bid & 7) * (NTILES / 8) + (bid >> 3);
  const int n0   = (tile & 3) * BN;
  const int m0   = (tile >> 2) * BM;

  __shared__ __align__(16) unsigned short As[BM * BK];      // 16 KB, single
  __shared__ __align__(16) unsigned short Bs[2][BM * BK];   // 32 KB, dbuf

  // A staging (f32 -> reg -> cvt -> swizzled LDS):
  const int lr = tid >> 4;
  const int lc = tid & 15;
  const float* aptr[8];
  int awoff[8];
#pragma unroll
  for (int p = 0; p < 8; ++p) {
    int row = p * 16 + lr;
    int gr  = m0 + row; if (gr > NNODE - 1) gr = NNODE - 1;   // clamp pad rows
    aptr[p]  = feat + (size_t)gr * D_IN + lc * 4;
    awoff[p] = swz(row, lc * 8);
  }

  // W staging via global_load_lds with pre-swizzled source (LDS dest linear)
  const unsigned short* srcW[4];
  int wdoff[4];
#pragma unroll
  for (int i = 0; i < 4; ++i) {
    int rl = wid * 32 + i * 8 + (lane >> 3);
    int g  = (lane & 7) ^ (rl & 7);
    srcW[i]  = Wb + (size_t)(n0 + rl) * D_IN + g * 8;
    wdoff[i] = (wid * 32 + i * 8) * 64;
  }

  f32x4 acc[4][4];
#pragma unroll
  for (int i = 0; i < 4; ++i)
#pragma unroll
    for (int j = 0; j < 4; ++j)
      acc[i][j] = (f32x4){0.f, 0.f, 0.f, 0.f};

  const int frow = lane & 15;
  const int kcb  = (lane >> 4) * 16;
  const int arow = wr * 64 + frow;
  const int brow = wc * 64 + frow;

  // ---- prologue: W(0) async; A(0) -> cvt -> As; A(1) in flight ----
  f32x4 aN[8];
  {
#pragma unroll
    for (int i = 0; i < 4; ++i) gld_lds16(srcW[i], &Bs[0][wdoff[i]]);
    f32x4 a0[8];
#pragma unroll
    for (int p = 0; p < 8; ++p) a0[p] = *(const f32x4*)(aptr[p]);
    // cvt forces compiler wait for A(0) (drains W(0) too -- prologue only)
#pragma unroll
    for (int p = 0; p < 8; ++p) {
      us4 v;
      v.x = f2bf(a0[p].x); v.y = f2bf(a0[p].y); v.z = f2bf(a0[p].z); v.w = f2bf(a0[p].w);
      *(us4*)((char*)As + awoff[p]) = v;
    }
#pragma unroll
    for (int p = 0; p < 8; ++p) aN[p] = *(const f32x4*)(aptr[p] + BK);  // A(1)
    SCHED0();
  }

  // ---- main loop: raw barriers, counted vmcnt (never 0 until last step) ----
#pragma unroll
  for (int ki = 0; ki < NK; ++ki) {
    const int cur = ki & 1;

    // issue next W tile (stays in flight across this step's barriers)
    if (ki < NK - 1) {
#pragma unroll
      for (int i = 0; i < 4; ++i) gld_lds16(srcW[i] + (ki + 1) * BK, &Bs[cur ^ 1][wdoff[i]]);
    }

    // top-of-step sync: W(ki) landed (counted), my As writes visible
    if (ki < NK - 1) { WAITVM12(); } else { WAITVM0(); }
    WAITLGKM0();
    SBAR();
    SCHED0();

    // MFMA on As (tile ki) and Bs[cur] (W(ki))
#pragma unroll
    for (int kk = 0; kk < 2; ++kk) {
      short8 af[4], bfr[4];
#pragma unroll
      for (int mi = 0; mi < 4; ++mi)
        af[mi] = *(const short8*)((const char*)As + swz(arow + mi * 16, kk * 64 + kcb));
#pragma unroll
      for (int ni = 0; ni < 4; ++ni)
        bfr[ni] = *(const short8*)((const char*)Bs[cur] + swz(brow + ni * 16, kk * 64 + kcb));
#pragma unroll
      for (int mi = 0; mi < 4; ++mi)
#pragma unroll
        for (int ni = 0; ni < 4; ++ni)
          acc[mi][ni] = __builtin_amdgcn_mfma_f32_16x16x32_bf16(af[mi], bfr[ni], acc[mi][ni], 0, 0, 0);
    }

    SBAR();            // WAR: all waves done reading As (exec barrier only)
    SCHED0();

    if (ki < NK - 1) {
      // cvt A(ki+1): compiler inserts counted vmcnt (~4) -- W(ki+1) stays in flight
#pragma unroll
      for (int p = 0; p < 8; ++p) {
        us4 v;
        v.x = f2bf(aN[p].x); v.y = f2bf(aN[p].y); v.z = f2bf(aN[p].z); v.w = f2bf(aN[p].w);
        *(us4*)((char*)As + awoff[p]) = v;
      }
      // issue A(ki+2) -- gets a full K-step of latency cover
      if (ki < NK - 2) {
#pragma unroll
        for (int p = 0; p < 8; ++p) aN[p] = *(const f32x4*)(aptr[p] + (ki + 2) * BK);
        SCHED0();
      }
    }
  }

  // ---- Epilogue: bias+ReLU -> bf16 via XOR-swizzled LDS overlay ----
  unsigned short* Cs = &Bs[0][0];   // 128x128 ushort = 32 KB overlay on Bs
  const int rq = lane >> 4;
#pragma unroll
  for (int ni = 0; ni < 4; ++ni) {
    int col = wc * 64 + ni * 16 + frow;
    float bv = bias[n0 + col];
#pragma unroll
    for (int mi = 0; mi < 4; ++mi) {
#pragma unroll
      for (int r = 0; r < 4; ++r) {
        int row = wr * 64 + mi * 16 + rq * 4 + r;
        int byt = row * 256 + ((col * 2) ^ ((row & 7) << 4));
        *(unsigned short*)((char*)Cs + byt) = f2bf(fmaxf(acc[mi][ni][r] + bv, 0.f));
      }
    }
  }
  __syncthreads();

  const int srow = tid >> 4;
  const int scol = (tid & 15) * 8;
#pragma unroll
  for (int it = 0; it < 8; ++it) {
    int row  = it * 16 + srow;
    int grow = m0 + row;
    int byt  = row * 256 + (((tid & 15) * 16) ^ ((row & 7) << 4));
    us8 v = *(const us8*)((const char*)Cs + byt);
    if (grow < NNODE)
      *(us8*)(Hb + (size_t)grow * D_H + n0 + scol) = v;
  }
}

// ---------------- Phase 2: out[b,:] = mean_s H[idx[b,s],:] ----------------
__global__ __launch_bounds__(256, 8)
void pool_mean4(const unsigned short* __restrict__ Hb,
                const int* __restrict__ nidx,
                float* __restrict__ out) {
  const int b4 = blockIdx.x;            // group of 4 output nodes
  const int q  = threadIdx.x >> 6;      // which node in group
  const int t  = threadIdx.x & 63;
  const int b  = b4 * 4 + q;

  __shared__ int rows[4][S_NB];
  if (threadIdx.x < 4 * S_NB)
    rows[threadIdx.x >> 5][threadIdx.x & 31] = nidx[b4 * 4 * S_NB + threadIdx.x];
  __syncthreads();

  const int c = t * 8;                  // 8 cols per thread (16B loads)
  float s0 = 0.f, s1 = 0.f, s2 = 0.f, s3 = 0.f;
  float s4 = 0.f, s5 = 0.f, s6 = 0.f, s7 = 0.f;
#pragma unroll
  for (int s = 0; s < S_NB; ++s) {
    us8 v = *(const us8*)(Hb + (size_t)rows[q][s] * D_H + c);
    s0 += bf2f(v[0]); s1 += bf2f(v[1]); s2 += bf2f(v[2]); s3 += bf2f(v[3]);
    s4 += bf2f(v[4]); s5 += bf2f(v[5]); s6 += bf2f(v[6]); s7 += bf2f(v[7]);
  }
  const float inv = 1.0f / (float)S_NB;
  f32x4 o1; o1.x = s0 * inv; o1.y = s1 * inv; o1.z = s2 * inv; o1.w = s3 * inv;
  f32x4 o2; o2.x = s4 * inv; o2.y = s5 * inv; o2.z = s6 * inv; o2.w = s7 * inv;
  *(f32x4*)(out + (size_t)b * D_H + c)     = o1;
  *(f32x4*)(out + (size_t)b * D_H + c + 4) = o2;
}

// ---------------- Fallback A: f32 reg-staged GEMM ----------------
__global__ __launch_bounds__(256, 4)
void gemm_h(const float* __restrict__ feat,
            const float* __restrict__ Wm,
            const float* __restrict__ bias,
            unsigned short* __restrict__ Hb) {
  const int tid  = threadIdx.x;
  const int lane = tid & 63;
  const int wid  = tid >> 6;
  const int wr   = wid >> 1;
  const int wc   = wid & 1;
  const int n0   = blockIdx.x * BN;
  const int m0   = blockIdx.y * BM;

  __shared__ __align__(16) unsigned short As[BM * BK];
  __shared__ __align__(16) unsigned short Bs[BM * BK];

  const int lr = tid >> 4;
  const int lc = tid & 15;

  const float* aptr[8];
  const float* wptr[8];
#pragma unroll
  for (int p = 0; p < 8; ++p) {
    int row = p * 16 + lr;
    int gr  = m0 + row; if (gr > NNODE - 1) gr = NNODE - 1;
    aptr[p] = feat + (size_t)gr * D_IN + lc * 4;
    wptr[p] = Wm + (size_t)(n0 + row) * D_IN + lc * 4;
  }

  f32x4 acc[4][4];
#pragma unroll
  for (int i = 0; i < 4; ++i)
#pragma unroll
    for (int j = 0; j < 4; ++j)
      acc[i][j] = (f32x4){0.f, 0.f, 0.f, 0.f};

  const int frow = lane & 15;
  const int kcb  = (lane >> 4) * 16;
  const int arow = wr * 64 + frow;
  const int brow = wc * 64 + frow;

  for (int k0 = 0; k0 < D_IN; k0 += BK) {
    __syncthreads();
#pragma unroll
    for (int p = 0; p < 8; ++p) {
      int row = p * 16 + lr;
      f32x4 av = *(const f32x4*)(aptr[p] + k0);
      f32x4 wv = *(const f32x4*)(wptr[p] + k0);
      us4 a4, w4;
      a4.x = f2bf(av.x); a4.y = f2bf(av.y); a4.z = f2bf(av.z); a4.w = f2bf(av.w);
      w4.x = f2bf(wv.x); w4.y = f2bf(wv.y); w4.z = f2bf(wv.z); w4.w = f2bf(wv.w);
      *(us4*)((char*)As + swz(row, lc * 8)) = a4;
      *(us4*)((char*)Bs + swz(row, lc * 8)) = w4;
    }
    __syncthreads();

#pragma unroll
    for (int kk = 0; kk < 2; ++kk) {
      short8 af[4], bfr[4];
#pragma unroll
      for (int mi = 0; mi < 4; ++mi)
        af[mi] = *(const short8*)((const char*)As + swz(arow + mi * 16, kk * 64 + kcb));
#pragma unroll
      for (int ni = 0; ni < 4; ++ni)
        bfr[ni] = *(const short8*)((const char*)Bs + swz(brow + ni * 16, kk * 64 + kcb));
#pragma unroll
      for (int mi = 0; mi < 4; ++mi)
#pragma unroll
        for (int ni = 0; ni < 4; ++ni)
          acc[mi][ni] = __builtin_amdgcn_mfma_f32_16x16x32_bf16(af[mi], bfr[ni], acc[mi][ni], 0, 0, 0);
    }
  }

  const int rq = lane >> 4;
#pragma unroll
  for (int ni = 0; ni < 4; ++ni) {
    int col = n0 + wc * 64 + ni * 16 + frow;
    float bv = bias[col];
#pragma unroll
    for (int mi = 0; mi < 4; ++mi) {
#pragma unroll
      for (int r = 0; r < 4; ++r) {
        int grow = m0 + wr * 64 + mi * 16 + rq * 4 + r;
        if (grow < NNODE)
          Hb[(size_t)grow * D_H + col] = f2bf(fmaxf(acc[mi][ni][r] + bv, 0.f));
      }
    }
  }
}

// ---------------- Fallback B: fused gathered GEMM (round-1) ----------------
__global__ __launch_bounds__(256, 4)
void pool_aggr_gemm(const int* __restrict__ nidx_g,
                    const float* __restrict__ feat,
                    const float* __restrict__ Wm,
                    const float* __restrict__ bias,
                    float* __restrict__ out) {
  const int tid  = threadIdx.x;
  const int lane = tid & 63;
  const int wid  = tid >> 6;
  const int wr   = wid >> 1;
  const int wc   = wid & 1;
  const int n0   = blockIdx.x * BN;
  const int mb   = blockIdx.y;

  __shared__ __align__(16) unsigned short As[BM * BK];
  __shared__ __align__(16) unsigned short Bs[BM * BK];
  __shared__ int nid[BM];

  if (tid < BM) nid[tid] = nidx_g[mb * BM + tid];
  __syncthreads();

  const int lr = tid >> 4;
  const int lc = tid & 15;

  const float* aptr[8];
  const float* wptr[8];
#pragma unroll
  for (int p = 0; p < 8; ++p) {
    int row = p * 16 + lr;
    aptr[p] = feat + (size_t)nid[row] * D_IN + lc * 4;
    wptr[p] = Wm + (size_t)(n0 + row) * D_IN + lc * 4;
  }

  f32x4 acc[4][4];
#pragma unroll
  for (int i = 0; i < 4; ++i)
#pragma unroll
    for (int j = 0; j < 4; ++j)
      acc[i][j] = (f32x4){0.f, 0.f, 0.f, 0.f};

  const int frow = lane & 15;
  const int kcb  = (lane >> 4) * 16;
  const int arow = wr * 64 + frow;
  const int brow = wc * 64 + frow;

  for (int k0 = 0; k0 < D_IN; k0 += BK) {
    __syncthreads();
#pragma unroll
    for (int p = 0; p < 8; ++p) {
      int row = p * 16 + lr;
      f32x4 av = *(const f32x4*)(aptr[p] + k0);
      f32x4 wv = *(const f32x4*)(wptr[p] + k0);
      us4 a4, w4;
      a4.x = f2bf(av.x); a4.y = f2bf(av.y); a4.z = f2bf(av.z); a4.w = f2bf(av.w);
      w4.x = f2bf(wv.x); w4.y = f2bf(wv.y); w4.z = f2bf(wv.z); w4.w = f2bf(wv.w);
      *(us4*)((char*)As + swz(row, lc * 8)) = a4;
      *(us4*)((char*)Bs + swz(row, lc * 8)) = w4;
    }
    __syncthreads();

#pragma unroll
    for (int kk = 0; kk < 2; ++kk) {
      short8 af[4], bfr[4];
#pragma unroll
      for (int mi = 0; mi < 4; ++mi)
        af[mi] = *(const short8*)((const char*)As + swz(arow + mi * 16, kk * 64 + kcb));
#pragma unroll
      for (int ni = 0; ni < 4; ++ni)
        bfr[ni] = *(const short8*)((const char*)Bs + swz(brow + ni * 16, kk * 64 + kcb));
#pragma unroll
      for (int mi = 0; mi < 4; ++mi)
#pragma unroll
        for (int ni = 0; ni < 4; ++ni)
          acc[mi][ni] = __builtin_amdgcn_mfma_f32_16x16x32_bf16(af[mi], bfr[ni], acc[mi][ni], 0, 0, 0);
    }
  }

  const int rq = lane >> 4;
#pragma unroll
  for (int ni = 0; ni < 4; ++ni) {
    int col = n0 + wc * 64 + ni * 16 + frow;
    float bv = bias[col];
#pragma unroll
    for (int bl = 0; bl < 2; ++bl) {
      float s = 0.f;
#pragma unroll
      for (int m2 = 0; m2 < 2; ++m2) {
        int mi = bl * 2 + m2;
#pragma unroll
        for (int r = 0; r < 4; ++r)
          s += fmaxf(acc[mi][ni][r] + bv, 0.f);
      }
      s += __shfl_xor(s, 16);
      s += __shfl_xor(s, 32);
      if (rq == 0) {
        int bb = mb * 4 + wr * 2 + bl;
        out[(size_t)bb * D_H + col] = s * (1.0f / (float)S_NB);
      }
    }
  }
}

extern "C" void kernel_launch(void* const* d_in, const int* in_sizes, int n_in,
                              void* d_out, int out_size, void* d_ws, size_t ws_size,
                              hipStream_t stream) {
  const int*   nidx = (const int*)d_in[0];    // [10000,32]
  const float* feat = (const float*)d_in[1];  // [100000,512]
  const float* Wm   = (const float*)d_in[2];  // [512,512]
  const float* bias = (const float*)d_in[3];  // [512]
  float* out = (float*)d_out;                 // [10000,512]

  const size_t wb_elems = (size_t)D_H * D_IN;                           // 262144
  const size_t wb_bytes = wb_elems * sizeof(unsigned short);            // 0.5 MB
  const size_t h_bytes  = (size_t)NNODE * D_H * sizeof(unsigned short); // 102.4 MB

  if (ws_size >= wb_bytes + h_bytes) {
    unsigned short* Wb = (unsigned short*)d_ws;
    unsigned short* Hb = Wb + wb_elems;
    cvt_bf16<<<128, 256, 0, stream>>>(Wm, Wb, D_H * D_IN / 8);
    gemm_hf3<<<NTILES, 256, 0, stream>>>(feat, Wb, bias, Hb);
    pool_mean4<<<NBATCH / 4, 256, 0, stream>>>(Hb, nidx, out);
  } else if (ws_size >= h_bytes) {
    unsigned short* Hb = (unsigned short*)d_ws;
    dim3 g1(D_H / BN, (NNODE + BM - 1) / BM);
    gemm_h<<<g1, 256, 0, stream>>>(feat, Wm, bias, Hb);
    pool_mean4<<<NBATCH / 4, 256, 0, stream>>>(Hb, nidx, out);
  } else {
    dim3 grid(D_H / BN, NBATCH / 4);
    pool_aggr_gemm<<<grid, 256, 0, stream>>>(nidx, feat, Wm, bias, out);
  }
}

// Round 8
// 191.841 us; speedup vs baseline: 1.2213x; 1.2213x over previous
//
#include <hip/hip_runtime.h>
#include <hip/hip_bf16.h>

// PoolAggregator: out[b,h] = mean_s relu( W @ features[idx[b,s]] + bias )
// B=10000, S=32, N=100000, D_IN=512, D_H=512.
//
// Pipeline (ws >= 103 MB):
//   0) cvt_bf16: W f32 -> Wb bf16 (0.5 MB) only.
//   1) gemm_f32a: H = relu(feat @ Wb^T + b) -> bf16.
//      A staged AS F32 via global_load_lds (DMA is dtype-agnostic) -> no reg
//      staging, no cvt pass over feat. f32->bf16 happens at LDS->reg fragment
//      read (v_cvt_pk via __float22bfloat162_rn). BK=32, A f32 dbuf (32KB) +
//      W bf16 packed-line dbuf (16KB) = 48KB -> 3 blocks/CU. m97 discipline:
//      issue next-tile DMA -> compute -> ONE __syncthreads per K-step.
//      All LDS tiles XOR-granule-swizzled (2-way max = free).
//   2) pool_mean4: out[b,:] = mean_s H[idx[b,s],:].
// Fallbacks: ws >= 102.4 MB -> f32-reg-staged gemm; else fused gather GEMM.

#define S_NB 32
#define D_IN 512
#define D_H  512
#define BM   128
#define BN   128
#define BK   32
#define NK   (D_IN / BK)            // 16
#define NNODE 100000
#define NBATCH 10000
#define NTILE_N 4
#define NTILE_M 784                 // padded so NTILES = 8 * 392, 392 % 4 == 0
#define NTILES  (NTILE_N * NTILE_M) // 3136

typedef __attribute__((ext_vector_type(8))) short  short8;
typedef __attribute__((ext_vector_type(4))) float  f32x4;
typedef __attribute__((ext_vector_type(4))) unsigned short us4;
typedef __attribute__((ext_vector_type(8))) unsigned short us8;

__device__ __forceinline__ unsigned short f2bf(float x) {
  union { float f; unsigned u; } v; v.f = x;
  unsigned r = v.u + 0x7FFFu + ((v.u >> 16) & 1u);
  return (unsigned short)(r >> 16);
}

__device__ __forceinline__ float bf2f(unsigned short x) {
  union { unsigned u; float f; } v; v.u = ((unsigned)x) << 16;
  return v.f;
}

// pack 8 f32 -> short8 of bf16 (RNE) via v_cvt_pk_bf16_f32
__device__ __forceinline__ short8 cvt8bf(f32x4 lo, f32x4 hi) {
  union { __hip_bfloat162 h; unsigned u; } c0, c1, c2, c3;
  c0.h = __float22bfloat162_rn(make_float2(lo.x, lo.y));
  c1.h = __float22bfloat162_rn(make_float2(lo.z, lo.w));
  c2.h = __float22bfloat162_rn(make_float2(hi.x, hi.y));
  c3.h = __float22bfloat162_rn(make_float2(hi.z, hi.w));
  union { unsigned u[4]; short8 s; } r;
  r.u[0] = c0.u; r.u[1] = c1.u; r.u[2] = c2.u; r.u[3] = c3.u;
  return r.s;
}

// byte offset into a [128][64]-bf16 LDS tile (row stride 128B) with XOR swizzle
// (used by fallback kernels)
__device__ __forceinline__ int swz(int row, int cb) {
  return row * 128 + (cb ^ ((row & 7) << 4));
}

// async global->LDS, 16B/lane; LDS dest wave-uniform base + lane*16
__device__ __forceinline__ void gld_lds16(const void* g, void* l) {
  __builtin_amdgcn_global_load_lds(
      (const __attribute__((address_space(1))) unsigned int*)g,
      (__attribute__((address_space(3))) unsigned int*)l, 16, 0, 0);
}

// ---------------- Phase 0: f32 -> bf16 (W only in primary path) ----------------
__global__ __launch_bounds__(256, 8)
void cvt_bf16(const float* __restrict__ src, unsigned short* __restrict__ dst, int n8) {
  int i = blockIdx.x * blockDim.x + threadIdx.x;
  const int stride = gridDim.x * blockDim.x;
  for (; i < n8; i += stride) {
    f32x4 a = *(const f32x4*)(src + (size_t)i * 8);
    f32x4 b = *(const f32x4*)(src + (size_t)i * 8 + 4);
    us8 o;
    o[0] = f2bf(a.x); o[1] = f2bf(a.y); o[2] = f2bf(a.z); o[3] = f2bf(a.w);
    o[4] = f2bf(b.x); o[5] = f2bf(b.y); o[6] = f2bf(b.z); o[7] = f2bf(b.w);
    *(us8*)(dst + (size_t)i * 8) = o;
  }
}

// ---------------- Phase 1: H = relu(feat @ Wb^T + b), A staged as f32 ----------------
__global__ __launch_bounds__(256, 3)
void gemm_f32a(const float* __restrict__ feat,
               const unsigned short* __restrict__ Wb,
               const float* __restrict__ bias,
               unsigned short* __restrict__ Hb) {
  const int tid  = threadIdx.x;
  const int lane = tid & 63;
  const int wid  = tid >> 6;
  const int wr   = wid >> 1;
  const int wc   = wid & 1;

  // XCD-chunked swizzle: XCD k (bid%8) gets 392 sequential tiles, n-tile fastest.
  const int bid  = blockIdx.x;
  const int tile = (bid & 7) * (NTILES / 8) + (bid >> 3);
  const int n0   = (tile & 3) * BN;
  const int m0   = (tile >> 2) * BM;

  __shared__ __align__(16) float          As[2][BM * BK];       // 2 x 16 KB (f32!)
  __shared__ __align__(16) unsigned short Ws[2][64 * 64];       // 2 x 8 KB, packed lines

  // ---- A staging: 4 DMA/wave, rows [32w+8i .. +7], granule-swizzled source ----
  const float* srcA[4];
  int dstAoff[4];                       // float offset of 8-row chunk
#pragma unroll
  for (int i = 0; i < 4; ++i) {
    int row = wid * 32 + i * 8 + (lane >> 3);
    int p   = lane & 7;
    int gr  = m0 + row; if (gr > NNODE - 1) gr = NNODE - 1;     // clamp pad rows
    srcA[i]   = feat + (size_t)gr * D_IN + (p ^ (row & 7)) * 4; // pre-swizzled src
    dstAoff[i] = (wid * 32 + i * 8) * BK;
  }

  // ---- W staging: 2 DMA/wave; line L = 2 W-rows; pos p holds q = p^(L&7) ----
  const unsigned short* srcW[2];
  int dstWoff[2];                       // ushort offset of 8-line chunk
#pragma unroll
  for (int i = 0; i < 2; ++i) {
    int c = wid * 2 + i;                // chunk 0..7
    int L = c * 8 + (lane >> 3);
    int p = lane & 7;
    int q = p ^ (L & 7);
    int rowbit = q >> 2, g0 = q & 3;
    srcW[i]   = Wb + (size_t)(n0 + L * 2 + rowbit) * D_IN + g0 * 8;
    dstWoff[i] = c * 512;               // 8 lines * 64 ushorts
  }

  f32x4 acc[4][4];
#pragma unroll
  for (int i = 0; i < 4; ++i)
#pragma unroll
    for (int j = 0; j < 4; ++j)
      acc[i][j] = (f32x4){0.f, 0.f, 0.f, 0.f};

  // ---- fragment-read geometry (all byte offsets static) ----
  const int frow = lane & 15;
  const int jg   = lane >> 4;            // k-chunk 0..3
  const int arow = wr * 64 + frow;
  // A: row stride 128B, granules g = (2jg+d)^(row&7); row&7 == frow&7 (mi*16 preserved)
  const int ag1 = ((2 * jg) ^ (frow & 7)) * 16;
  const int ag2 = ((2 * jg + 1) ^ (frow & 7)) * 16;
  // W: line = wc*32 + (frow>>1) + ni*8 ; pos = ((frow&1)*4 + jg) ^ (line&7), line&7 == (frow>>1)&7
  const int wp  = ((((frow & 1) << 2) + jg) ^ ((frow >> 1) & 7)) * 16;
  const int wlb = wc * 32 + (frow >> 1);

  // ---- prologue: stage K-tile 0 ----
#pragma unroll
  for (int i = 0; i < 4; ++i) gld_lds16(srcA[i], &As[0][dstAoff[i]]);
#pragma unroll
  for (int i = 0; i < 2; ++i) gld_lds16(srcW[i], &Ws[0][dstWoff[i]]);
  __syncthreads();

  // ---- main loop: one __syncthreads per K-step (m97 discipline) ----
#pragma unroll
  for (int ki = 0; ki < NK; ++ki) {
    const int cur = ki & 1;

    if (ki < NK - 1) {
#pragma unroll
      for (int i = 0; i < 4; ++i)
        gld_lds16(srcA[i] + (ki + 1) * BK, &As[cur ^ 1][dstAoff[i]]);
#pragma unroll
      for (int i = 0; i < 2; ++i)
        gld_lds16(srcW[i] + (ki + 1) * BK, &Ws[cur ^ 1][dstWoff[i]]);
    }

    short8 af[4], bfr[4];
#pragma unroll
    for (int mi = 0; mi < 4; ++mi) {
      const char* base = (const char*)&As[cur][0] + (arow + mi * 16) * 128;
      f32x4 lo = *(const f32x4*)(base + ag1);
      f32x4 hi = *(const f32x4*)(base + ag2);
      af[mi] = cvt8bf(lo, hi);
    }
#pragma unroll
    for (int ni = 0; ni < 4; ++ni) {
      const char* base = (const char*)&Ws[cur][0] + (wlb + ni * 8) * 128;
      bfr[ni] = *(const short8*)(base + wp);
    }
#pragma unroll
    for (int mi = 0; mi < 4; ++mi)
#pragma unroll
      for (int ni = 0; ni < 4; ++ni)
        acc[mi][ni] = __builtin_amdgcn_mfma_f32_16x16x32_bf16(af[mi], bfr[ni], acc[mi][ni], 0, 0, 0);

    __syncthreads();   // next-tile DMA landed; this tile's reads done (WAR)
  }

  // ---- Epilogue: bias+ReLU -> bf16 via XOR-swizzled LDS overlay ----
  unsigned short* Cs = (unsigned short*)&As[0][0];   // 32 KB overlay
  const int rq = lane >> 4;
#pragma unroll
  for (int ni = 0; ni < 4; ++ni) {
    int col = wc * 64 + ni * 16 + frow;
    float bv = bias[n0 + col];
#pragma unroll
    for (int mi = 0; mi < 4; ++mi) {
#pragma unroll
      for (int r = 0; r < 4; ++r) {
        int row = wr * 64 + mi * 16 + rq * 4 + r;
        int byt = row * 256 + ((col * 2) ^ ((row & 7) << 4));
        *(unsigned short*)((char*)Cs + byt) = f2bf(fmaxf(acc[mi][ni][r] + bv, 0.f));
      }
    }
  }
  __syncthreads();

  const int srow = tid >> 4;
  const int scol = (tid & 15) * 8;
#pragma unroll
  for (int it = 0; it < 8; ++it) {
    int row  = it * 16 + srow;
    int grow = m0 + row;
    int byt  = row * 256 + (((tid & 15) * 16) ^ ((row & 7) << 4));
    us8 v = *(const us8*)((const char*)Cs + byt);
    if (grow < NNODE)
      *(us8*)(Hb + (size_t)grow * D_H + n0 + scol) = v;
  }
}

// ---------------- Phase 2: out[b,:] = mean_s H[idx[b,s],:] ----------------
__global__ __launch_bounds__(256, 8)
void pool_mean4(const unsigned short* __restrict__ Hb,
                const int* __restrict__ nidx,
                float* __restrict__ out) {
  const int b4 = blockIdx.x;            // group of 4 output nodes
  const int q  = threadIdx.x >> 6;      // which node in group
  const int t  = threadIdx.x & 63;
  const int b  = b4 * 4 + q;

  __shared__ int rows[4][S_NB];
  if (threadIdx.x < 4 * S_NB)
    rows[threadIdx.x >> 5][threadIdx.x & 31] = nidx[b4 * 4 * S_NB + threadIdx.x];
  __syncthreads();

  const int c = t * 8;                  // 8 cols per thread (16B loads)
  float s0 = 0.f, s1 = 0.f, s2 = 0.f, s3 = 0.f;
  float s4 = 0.f, s5 = 0.f, s6 = 0.f, s7 = 0.f;
#pragma unroll
  for (int s = 0; s < S_NB; ++s) {
    us8 v = *(const us8*)(Hb + (size_t)rows[q][s] * D_H + c);
    s0 += bf2f(v[0]); s1 += bf2f(v[1]); s2 += bf2f(v[2]); s3 += bf2f(v[3]);
    s4 += bf2f(v[4]); s5 += bf2f(v[5]); s6 += bf2f(v[6]); s7 += bf2f(v[7]);
  }
  const float inv = 1.0f / (float)S_NB;
  f32x4 o1; o1.x = s0 * inv; o1.y = s1 * inv; o1.z = s2 * inv; o1.w = s3 * inv;
  f32x4 o2; o2.x = s4 * inv; o2.y = s5 * inv; o2.z = s6 * inv; o2.w = s7 * inv;
  *(f32x4*)(out + (size_t)b * D_H + c)     = o1;
  *(f32x4*)(out + (size_t)b * D_H + c + 4) = o2;
}

// ---------------- Fallback A: f32 reg-staged GEMM ----------------
__global__ __launch_bounds__(256, 4)
void gemm_h(const float* __restrict__ feat,
            const float* __restrict__ Wm,
            const float* __restrict__ bias,
            unsigned short* __restrict__ Hb) {
  const int tid  = threadIdx.x;
  const int lane = tid & 63;
  const int wid  = tid >> 6;
  const int wr   = wid >> 1;
  const int wc   = wid & 1;
  const int n0   = blockIdx.x * BN;
  const int m0   = blockIdx.y * BM;

  __shared__ __align__(16) unsigned short As[BM * 64];
  __shared__ __align__(16) unsigned short Bs[BM * 64];

  const int lr = tid >> 4;
  const int lc = tid & 15;

  const float* aptr[8];
  const float* wptr[8];
#pragma unroll
  for (int p = 0; p < 8; ++p) {
    int row = p * 16 + lr;
    int gr  = m0 + row; if (gr > NNODE - 1) gr = NNODE - 1;
    aptr[p] = feat + (size_t)gr * D_IN + lc * 4;
    wptr[p] = Wm + (size_t)(n0 + row) * D_IN + lc * 4;
  }

  f32x4 acc[4][4];
#pragma unroll
  for (int i = 0; i < 4; ++i)
#pragma unroll
    for (int j = 0; j < 4; ++j)
      acc[i][j] = (f32x4){0.f, 0.f, 0.f, 0.f};

  const int frow = lane & 15;
  const int kcb  = (lane >> 4) * 16;
  const int arow = wr * 64 + frow;
  const int brow = wc * 64 + frow;

  for (int k0 = 0; k0 < D_IN; k0 += 64) {
    __syncthreads();
#pragma unroll
    for (int p = 0; p < 8; ++p) {
      int row = p * 16 + lr;
      f32x4 av = *(const f32x4*)(aptr[p] + k0);
      f32x4 wv = *(const f32x4*)(wptr[p] + k0);
      us4 a4, w4;
      a4.x = f2bf(av.x); a4.y = f2bf(av.y); a4.z = f2bf(av.z); a4.w = f2bf(av.w);
      w4.x = f2bf(wv.x); w4.y = f2bf(wv.y); w4.z = f2bf(wv.z); w4.w = f2bf(wv.w);
      *(us4*)((char*)As + swz(row, lc * 8)) = a4;
      *(us4*)((char*)Bs + swz(row, lc * 8)) = w4;
    }
    __syncthreads();

#pragma unroll
    for (int kk = 0; kk < 2; ++kk) {
      short8 af[4], bfr[4];
#pragma unroll
      for (int mi = 0; mi < 4; ++mi)
        af[mi] = *(const short8*)((const char*)As + swz(arow + mi * 16, kk * 64 + kcb));
#pragma unroll
      for (int ni = 0; ni < 4; ++ni)
        bfr[ni] = *(const short8*)((const char*)Bs + swz(brow + ni * 16, kk * 64 + kcb));
#pragma unroll
      for (int mi = 0; mi < 4; ++mi)
#pragma unroll
        for (int ni = 0; ni < 4; ++ni)
          acc[mi][ni] = __builtin_amdgcn_mfma_f32_16x16x32_bf16(af[mi], bfr[ni], acc[mi][ni], 0, 0, 0);
    }
  }

  const int rq = lane >> 4;
#pragma unroll
  for (int ni = 0; ni < 4; ++ni) {
    int col = n0 + wc * 64 + ni * 16 + frow;
    float bv = bias[col];
#pragma unroll
    for (int mi = 0; mi < 4; ++mi) {
#pragma unroll
      for (int r = 0; r < 4; ++r) {
        int grow = m0 + wr * 64 + mi * 16 + rq * 4 + r;
        if (grow < NNODE)
          Hb[(size_t)grow * D_H + col] = f2bf(fmaxf(acc[mi][ni][r] + bv, 0.f));
      }
    }
  }
}

// ---------------- Fallback B: fused gathered GEMM (round-1) ----------------
__global__ __launch_bounds__(256, 4)
void pool_aggr_gemm(const int* __restrict__ nidx_g,
                    const float* __restrict__ feat,
                    const float* __restrict__ Wm,
                    const float* __restrict__ bias,
                    float* __restrict__ out) {
  const int tid  = threadIdx.x;
  const int lane = tid & 63;
  const int wid  = tid >> 6;
  const int wr   = wid >> 1;
  const int wc   = wid & 1;
  const int n0   = blockIdx.x * BN;
  const int mb   = blockIdx.y;

  __shared__ __align__(16) unsigned short As[BM * 64];
  __shared__ __align__(16) unsigned short Bs[BM * 64];
  __shared__ int nid[BM];

  if (tid < BM) nid[tid] = nidx_g[mb * BM + tid];
  __syncthreads();

  const int lr = tid >> 4;
  const int lc = tid & 15;

  const float* aptr[8];
  const float* wptr[8];
#pragma unroll
  for (int p = 0; p < 8; ++p) {
    int row = p * 16 + lr;
    aptr[p] = feat + (size_t)nid[row] * D_IN + lc * 4;
    wptr[p] = Wm + (size_t)(n0 + row) * D_IN + lc * 4;
  }

  f32x4 acc[4][4];
#pragma unroll
  for (int i = 0; i < 4; ++i)
#pragma unroll
    for (int j = 0; j < 4; ++j)
      acc[i][j] = (f32x4){0.f, 0.f, 0.f, 0.f};

  const int frow = lane & 15;
  const int kcb  = (lane >> 4) * 16;
  const int arow = wr * 64 + frow;
  const int brow = wc * 64 + frow;

  for (int k0 = 0; k0 < D_IN; k0 += 64) {
    __syncthreads();
#pragma unroll
    for (int p = 0; p < 8; ++p) {
      int row = p * 16 + lr;
      f32x4 av = *(const f32x4*)(aptr[p] + k0);
      f32x4 wv = *(const f32x4*)(wptr[p] + k0);
      us4 a4, w4;
      a4.x = f2bf(av.x); a4.y = f2bf(av.y); a4.z = f2bf(av.z); a4.w = f2bf(av.w);
      w4.x = f2bf(wv.x); w4.y = f2bf(wv.y); w4.z = f2bf(wv.z); w4.w = f2bf(wv.w);
      *(us4*)((char*)As + swz(row, lc * 8)) = a4;
      *(us4*)((char*)Bs + swz(row, lc * 8)) = w4;
    }
    __syncthreads();

#pragma unroll
    for (int kk = 0; kk < 2; ++kk) {
      short8 af[4], bfr[4];
#pragma unroll
      for (int mi = 0; mi < 4; ++mi)
        af[mi] = *(const short8*)((const char*)As + swz(arow + mi * 16, kk * 64 + kcb));
#pragma unroll
      for (int ni = 0; ni < 4; ++ni)
        bfr[ni] = *(const short8*)((const char*)Bs + swz(brow + ni * 16, kk * 64 + kcb));
#pragma unroll
      for (int mi = 0; mi < 4; ++mi)
#pragma unroll
        for (int ni = 0; ni < 4; ++ni)
          acc[mi][ni] = __builtin_amdgcn_mfma_f32_16x16x32_bf16(af[mi], bfr[ni], acc[mi][ni], 0, 0, 0);
    }
  }

  const int rq = lane >> 4;
#pragma unroll
  for (int ni = 0; ni < 4; ++ni) {
    int col = n0 + wc * 64 + ni * 16 + frow;
    float bv = bias[col];
#pragma unroll
    for (int bl = 0; bl < 2; ++bl) {
      float s = 0.f;
#pragma unroll
      for (int m2 = 0; m2 < 2; ++m2) {
        int mi = bl * 2 + m2;
#pragma unroll
        for (int r = 0; r < 4; ++r)
          s += fmaxf(acc[mi][ni][r] + bv, 0.f);
      }
      s += __shfl_xor(s, 16);
      s += __shfl_xor(s, 32);
      if (rq == 0) {
        int bb = mb * 4 + wr * 2 + bl;
        out[(size_t)bb * D_H + col] = s * (1.0f / (float)S_NB);
      }
    }
  }
}

extern "C" void kernel_launch(void* const* d_in, const int* in_sizes, int n_in,
                              void* d_out, int out_size, void* d_ws, size_t ws_size,
                              hipStream_t stream) {
  const int*   nidx = (const int*)d_in[0];    // [10000,32]
  const float* feat = (const float*)d_in[1];  // [100000,512]
  const float* Wm   = (const float*)d_in[2];  // [512,512]
  const float* bias = (const float*)d_in[3];  // [512]
  float* out = (float*)d_out;                 // [10000,512]

  const size_t wb_elems = (size_t)D_H * D_IN;                           // 262144
  const size_t wb_bytes = wb_elems * sizeof(unsigned short);            // 0.5 MB
  const size_t h_bytes  = (size_t)NNODE * D_H * sizeof(unsigned short); // 102.4 MB

  if (ws_size >= wb_bytes + h_bytes) {
    unsigned short* Wb = (unsigned short*)d_ws;
    unsigned short* Hb = Wb + wb_elems;
    cvt_bf16<<<128, 256, 0, stream>>>(Wm, Wb, D_H * D_IN / 8);
    gemm_f32a<<<NTILES, 256, 0, stream>>>(feat, Wb, bias, Hb);
    pool_mean4<<<NBATCH / 4, 256, 0, stream>>>(Hb, nidx, out);
  } else if (ws_size >= h_bytes) {
    unsigned short* Hb = (unsigned short*)d_ws;
    dim3 g1(D_H / BN, (NNODE + BM - 1) / BM);
    gemm_h<<<g1, 256, 0, stream>>>(feat, Wm, bias, Hb);
    pool_mean4<<<NBATCH / 4, 256, 0, stream>>>(Hb, nidx, out);
  } else {
    dim3 grid(D_H / BN, NBATCH / 4);
    pool_aggr_gemm<<<grid, 256, 0, stream>>>(nidx, feat, Wm, bias, out);
  }
}

// Round 9
// 185.633 us; speedup vs baseline: 1.2621x; 1.0334x over previous
//
#include <hip/hip_runtime.h>
#include <hip/hip_bf16.h>

// PoolAggregator: out[b,h] = mean_s relu( W @ features[idx[b,s]] + bias )
// B=10000, S=32, N=100000, D_IN=512, D_H=512.
//
// Pipeline (ws >= 103 MB):
//   0) cvt_bf16: W f32 -> Wb bf16 (0.5 MB) only.
//   1) gemm_f32c: H = relu(feat @ Wb^T + b) -> bf16.
//      A staged AS F32 via global_load_lds (no reg staging, no spill risk);
//      f32->bf16 at LDS->reg fragment read (v_cvt_pk). BK=32, 48KB LDS,
//      3 blocks/CU. T4 pipeline: counted s_waitcnt vmcnt(6) + two raw
//      s_barriers per K-step -- next-step DMAs stay in flight across the
//      MFMA phase (never drained mid-loop).
//   2) pool_mean4: out[b,:] = mean_s H[idx[b,s],:].
// Fallbacks: ws >= 102.4 MB -> f32-reg-staged gemm; else fused gather GEMM.

#define S_NB 32
#define D_IN 512
#define D_H  512
#define BM   128
#define BN   128
#define BK   32
#define NK   (D_IN / BK)            // 16
#define NNODE 100000
#define NBATCH 10000
#define NTILE_N 4
#define NTILE_M 784                 // padded so NTILES = 8 * 392, 392 % 4 == 0
#define NTILES  (NTILE_N * NTILE_M) // 3136

typedef __attribute__((ext_vector_type(8))) short  short8;
typedef __attribute__((ext_vector_type(4))) float  f32x4;
typedef __attribute__((ext_vector_type(4))) unsigned short us4;
typedef __attribute__((ext_vector_type(8))) unsigned short us8;

__device__ __forceinline__ unsigned short f2bf(float x) {
  union { float f; unsigned u; } v; v.f = x;
  unsigned r = v.u + 0x7FFFu + ((v.u >> 16) & 1u);
  return (unsigned short)(r >> 16);
}

__device__ __forceinline__ float bf2f(unsigned short x) {
  union { unsigned u; float f; } v; v.u = ((unsigned)x) << 16;
  return v.f;
}

// pack 8 f32 -> short8 of bf16 (RNE) via v_cvt_pk_bf16_f32
__device__ __forceinline__ short8 cvt8bf(f32x4 lo, f32x4 hi) {
  union { __hip_bfloat162 h; unsigned u; } c0, c1, c2, c3;
  c0.h = __float22bfloat162_rn(make_float2(lo.x, lo.y));
  c1.h = __float22bfloat162_rn(make_float2(lo.z, lo.w));
  c2.h = __float22bfloat162_rn(make_float2(hi.x, hi.y));
  c3.h = __float22bfloat162_rn(make_float2(hi.z, hi.w));
  union { unsigned u[4]; short8 s; } r;
  r.u[0] = c0.u; r.u[1] = c1.u; r.u[2] = c2.u; r.u[3] = c3.u;
  return r.s;
}

// byte offset into a [128][64]-bf16 LDS tile (row stride 128B) with XOR swizzle
// (used by fallback kernels)
__device__ __forceinline__ int swz(int row, int cb) {
  return row * 128 + (cb ^ ((row & 7) << 4));
}

// async global->LDS, 16B/lane; LDS dest wave-uniform base + lane*16
__device__ __forceinline__ void gld_lds16(const void* g, void* l) {
  __builtin_amdgcn_global_load_lds(
      (const __attribute__((address_space(1))) unsigned int*)g,
      (__attribute__((address_space(3))) unsigned int*)l, 16, 0, 0);
}

// ---------------- Phase 0: f32 -> bf16 (W only in primary path) ----------------
__global__ __launch_bounds__(256, 8)
void cvt_bf16(const float* __restrict__ src, unsigned short* __restrict__ dst, int n8) {
  int i = blockIdx.x * blockDim.x + threadIdx.x;
  const int stride = gridDim.x * blockDim.x;
  for (; i < n8; i += stride) {
    f32x4 a = *(const f32x4*)(src + (size_t)i * 8);
    f32x4 b = *(const f32x4*)(src + (size_t)i * 8 + 4);
    us8 o;
    o[0] = f2bf(a.x); o[1] = f2bf(a.y); o[2] = f2bf(a.z); o[3] = f2bf(a.w);
    o[4] = f2bf(b.x); o[5] = f2bf(b.y); o[6] = f2bf(b.z); o[7] = f2bf(b.w);
    *(us8*)(dst + (size_t)i * 8) = o;
  }
}

// ---------------- Phase 1: H = relu(feat @ Wb^T + b), A staged as f32, T4 ----------------
__global__ __launch_bounds__(256, 3)
void gemm_f32c(const float* __restrict__ feat,
               const unsigned short* __restrict__ Wb,
               const float* __restrict__ bias,
               unsigned short* __restrict__ Hb) {
  const int tid  = threadIdx.x;
  const int lane = tid & 63;
  const int wid  = tid >> 6;
  const int wr   = wid >> 1;
  const int wc   = wid & 1;

  // XCD-chunked swizzle: XCD k (bid%8) gets 392 sequential tiles, n-tile fastest.
  const int bid  = blockIdx.x;
  const int tile = (bid & 7) * (NTILES / 8) + (bid >> 3);
  const int n0   = (tile & 3) * BN;
  const int m0   = (tile >> 2) * BM;

  __shared__ __align__(16) float          As[2][BM * BK];       // 2 x 16 KB (f32!)
  __shared__ __align__(16) unsigned short Ws[2][64 * 64];       // 2 x 8 KB, packed lines

  // ---- A staging: 4 DMA/wave, rows [32w+8i .. +7], granule-swizzled source ----
  const float* srcA[4];
  int dstAoff[4];                       // float offset of 8-row chunk
#pragma unroll
  for (int i = 0; i < 4; ++i) {
    int row = wid * 32 + i * 8 + (lane >> 3);
    int p   = lane & 7;
    int gr  = m0 + row; if (gr > NNODE - 1) gr = NNODE - 1;     // clamp pad rows
    srcA[i]   = feat + (size_t)gr * D_IN + (p ^ (row & 7)) * 4; // pre-swizzled src
    dstAoff[i] = (wid * 32 + i * 8) * BK;
  }

  // ---- W staging: 2 DMA/wave; line L = 2 W-rows; pos p holds q = p^(L&7) ----
  const unsigned short* srcW[2];
  int dstWoff[2];                       // ushort offset of 8-line chunk
#pragma unroll
  for (int i = 0; i < 2; ++i) {
    int c = wid * 2 + i;                // chunk 0..7
    int L = c * 8 + (lane >> 3);
    int p = lane & 7;
    int q = p ^ (L & 7);
    int rowbit = q >> 2, g0 = q & 3;
    srcW[i]   = Wb + (size_t)(n0 + L * 2 + rowbit) * D_IN + g0 * 8;
    dstWoff[i] = c * 512;               // 8 lines * 64 ushorts
  }

  f32x4 acc[4][4];
#pragma unroll
  for (int i = 0; i < 4; ++i)
#pragma unroll
    for (int j = 0; j < 4; ++j)
      acc[i][j] = (f32x4){0.f, 0.f, 0.f, 0.f};

  // ---- fragment-read geometry (all byte offsets static) ----
  const int frow = lane & 15;
  const int jg   = lane >> 4;            // k-chunk 0..3
  const int arow = wr * 64 + frow;
  const int ag1 = ((2 * jg) ^ (frow & 7)) * 16;
  const int ag2 = ((2 * jg + 1) ^ (frow & 7)) * 16;
  const int wp  = ((((frow & 1) << 2) + jg) ^ ((frow >> 1) & 7)) * 16;
  const int wlb = wc * 32 + (frow >> 1);

  // ---- prologue: issue K-tile 0 DMAs (stay in flight into the loop) ----
#pragma unroll
  for (int i = 0; i < 4; ++i) gld_lds16(srcA[i], &As[0][dstAoff[i]]);
#pragma unroll
  for (int i = 0; i < 2; ++i) gld_lds16(srcW[i], &Ws[0][dstWoff[i]]);

  // ---- main loop: counted vmcnt + 2 raw barriers per K-step (T4) ----
#pragma unroll
  for (int ki = 0; ki < NK; ++ki) {
    const int cur = ki & 1;

    // issue next-tile DMAs into the other buffer (safe: barrier-B of step
    // ki-1 guarantees all waves finished reading it)
    if (ki < NK - 1) {
#pragma unroll
      for (int i = 0; i < 4; ++i)
        gld_lds16(srcA[i] + (ki + 1) * BK, &As[cur ^ 1][dstAoff[i]]);
#pragma unroll
      for (int i = 0; i < 2; ++i)
        gld_lds16(srcW[i] + (ki + 1) * BK, &Ws[cur ^ 1][dstWoff[i]]);
      asm volatile("s_waitcnt vmcnt(6)" ::: "memory");  // my DMA(ki) landed; DMA(ki+1) in flight
    } else {
      asm volatile("s_waitcnt vmcnt(0)" ::: "memory");  // last tile: drain
    }
    __builtin_amdgcn_s_barrier();                       // barrier-A: everyone's DMA(ki) visible
    __builtin_amdgcn_sched_barrier(0);

    // ds_read + cvt + MFMA on buf[cur]
    short8 af[4], bfr[4];
#pragma unroll
    for (int mi = 0; mi < 4; ++mi) {
      const char* base = (const char*)&As[cur][0] + (arow + mi * 16) * 128;
      f32x4 lo = *(const f32x4*)(base + ag1);
      f32x4 hi = *(const f32x4*)(base + ag2);
      af[mi] = cvt8bf(lo, hi);
    }
#pragma unroll
    for (int ni = 0; ni < 4; ++ni) {
      const char* base = (const char*)&Ws[cur][0] + (wlb + ni * 8) * 128;
      bfr[ni] = *(const short8*)(base + wp);
    }
#pragma unroll
    for (int mi = 0; mi < 4; ++mi)
#pragma unroll
      for (int ni = 0; ni < 4; ++ni)
        acc[mi][ni] = __builtin_amdgcn_mfma_f32_16x16x32_bf16(af[mi], bfr[ni], acc[mi][ni], 0, 0, 0);

    asm volatile("s_waitcnt lgkmcnt(0)" ::: "memory");  // my LDS reads retired
    __builtin_amdgcn_s_barrier();                       // barrier-B: buf[cur] reusable
    __builtin_amdgcn_sched_barrier(0);
  }

  // ---- Epilogue: bias+ReLU -> bf16 via XOR-swizzled LDS overlay ----
  unsigned short* Cs = (unsigned short*)&As[0][0];   // 32 KB overlay
  const int rq = lane >> 4;
#pragma unroll
  for (int ni = 0; ni < 4; ++ni) {
    int col = wc * 64 + ni * 16 + frow;
    float bv = bias[n0 + col];
#pragma unroll
    for (int mi = 0; mi < 4; ++mi) {
#pragma unroll
      for (int r = 0; r < 4; ++r) {
        int row = wr * 64 + mi * 16 + rq * 4 + r;
        int byt = row * 256 + ((col * 2) ^ ((row & 7) << 4));
        *(unsigned short*)((char*)Cs + byt) = f2bf(fmaxf(acc[mi][ni][r] + bv, 0.f));
      }
    }
  }
  __syncthreads();

  const int srow = tid >> 4;
  const int scol = (tid & 15) * 8;
#pragma unroll
  for (int it = 0; it < 8; ++it) {
    int row  = it * 16 + srow;
    int grow = m0 + row;
    int byt  = row * 256 + (((tid & 15) * 16) ^ ((row & 7) << 4));
    us8 v = *(const us8*)((const char*)Cs + byt);
    if (grow < NNODE)
      *(us8*)(Hb + (size_t)grow * D_H + n0 + scol) = v;
  }
}

// ---------------- Phase 2: out[b,:] = mean_s H[idx[b,s],:] ----------------
__global__ __launch_bounds__(256, 8)
void pool_mean4(const unsigned short* __restrict__ Hb,
                const int* __restrict__ nidx,
                float* __restrict__ out) {
  const int b4 = blockIdx.x;            // group of 4 output nodes
  const int q  = threadIdx.x >> 6;      // which node in group
  const int t  = threadIdx.x & 63;
  const int b  = b4 * 4 + q;

  __shared__ int rows[4][S_NB];
  if (threadIdx.x < 4 * S_NB)
    rows[threadIdx.x >> 5][threadIdx.x & 31] = nidx[b4 * 4 * S_NB + threadIdx.x];
  __syncthreads();

  const int c = t * 8;                  // 8 cols per thread (16B loads)
  float s0 = 0.f, s1 = 0.f, s2 = 0.f, s3 = 0.f;
  float s4 = 0.f, s5 = 0.f, s6 = 0.f, s7 = 0.f;
#pragma unroll
  for (int s = 0; s < S_NB; ++s) {
    us8 v = *(const us8*)(Hb + (size_t)rows[q][s] * D_H + c);
    s0 += bf2f(v[0]); s1 += bf2f(v[1]); s2 += bf2f(v[2]); s3 += bf2f(v[3]);
    s4 += bf2f(v[4]); s5 += bf2f(v[5]); s6 += bf2f(v[6]); s7 += bf2f(v[7]);
  }
  const float inv = 1.0f / (float)S_NB;
  f32x4 o1; o1.x = s0 * inv; o1.y = s1 * inv; o1.z = s2 * inv; o1.w = s3 * inv;
  f32x4 o2; o2.x = s4 * inv; o2.y = s5 * inv; o2.z = s6 * inv; o2.w = s7 * inv;
  *(f32x4*)(out + (size_t)b * D_H + c)     = o1;
  *(f32x4*)(out + (size_t)b * D_H + c + 4) = o2;
}

// ---------------- Fallback A: f32 reg-staged GEMM ----------------
__global__ __launch_bounds__(256, 4)
void gemm_h(const float* __restrict__ feat,
            const float* __restrict__ Wm,
            const float* __restrict__ bias,
            unsigned short* __restrict__ Hb) {
  const int tid  = threadIdx.x;
  const int lane = tid & 63;
  const int wid  = tid >> 6;
  const int wr   = wid >> 1;
  const int wc   = wid & 1;
  const int n0   = blockIdx.x * BN;
  const int m0   = blockIdx.y * BM;

  __shared__ __align__(16) unsigned short As[BM * 64];
  __shared__ __align__(16) unsigned short Bs[BM * 64];

  const int lr = tid >> 4;
  const int lc = tid & 15;

  const float* aptr[8];
  const float* wptr[8];
#pragma unroll
  for (int p = 0; p < 8; ++p) {
    int row = p * 16 + lr;
    int gr  = m0 + row; if (gr > NNODE - 1) gr = NNODE - 1;
    aptr[p] = feat + (size_t)gr * D_IN + lc * 4;
    wptr[p] = Wm + (size_t)(n0 + row) * D_IN + lc * 4;
  }

  f32x4 acc[4][4];
#pragma unroll
  for (int i = 0; i < 4; ++i)
#pragma unroll
    for (int j = 0; j < 4; ++j)
      acc[i][j] = (f32x4){0.f, 0.f, 0.f, 0.f};

  const int frow = lane & 15;
  const int kcb  = (lane >> 4) * 16;
  const int arow = wr * 64 + frow;
  const int brow = wc * 64 + frow;

  for (int k0 = 0; k0 < D_IN; k0 += 64) {
    __syncthreads();
#pragma unroll
    for (int p = 0; p < 8; ++p) {
      int row = p * 16 + lr;
      f32x4 av = *(const f32x4*)(aptr[p] + k0);
      f32x4 wv = *(const f32x4*)(wptr[p] + k0);
      us4 a4, w4;
      a4.x = f2bf(av.x); a4.y = f2bf(av.y); a4.z = f2bf(av.z); a4.w = f2bf(av.w);
      w4.x = f2bf(wv.x); w4.y = f2bf(wv.y); w4.z = f2bf(wv.z); w4.w = f2bf(wv.w);
      *(us4*)((char*)As + swz(row, lc * 8)) = a4;
      *(us4*)((char*)Bs + swz(row, lc * 8)) = w4;
    }
    __syncthreads();

#pragma unroll
    for (int kk = 0; kk < 2; ++kk) {
      short8 af[4], bfr[4];
#pragma unroll
      for (int mi = 0; mi < 4; ++mi)
        af[mi] = *(const short8*)((const char*)As + swz(arow + mi * 16, kk * 64 + kcb));
#pragma unroll
      for (int ni = 0; ni < 4; ++ni)
        bfr[ni] = *(const short8*)((const char*)Bs + swz(brow + ni * 16, kk * 64 + kcb));
#pragma unroll
      for (int mi = 0; mi < 4; ++mi)
#pragma unroll
        for (int ni = 0; ni < 4; ++ni)
          acc[mi][ni] = __builtin_amdgcn_mfma_f32_16x16x32_bf16(af[mi], bfr[ni], acc[mi][ni], 0, 0, 0);
    }
  }

  const int rq = lane >> 4;
#pragma unroll
  for (int ni = 0; ni < 4; ++ni) {
    int col = n0 + wc * 64 + ni * 16 + frow;
    float bv = bias[col];
#pragma unroll
    for (int mi = 0; mi < 4; ++mi) {
#pragma unroll
      for (int r = 0; r < 4; ++r) {
        int grow = m0 + wr * 64 + mi * 16 + rq * 4 + r;
        if (grow < NNODE)
          Hb[(size_t)grow * D_H + col] = f2bf(fmaxf(acc[mi][ni][r] + bv, 0.f));
      }
    }
  }
}

// ---------------- Fallback B: fused gathered GEMM (round-1) ----------------
__global__ __launch_bounds__(256, 4)
void pool_aggr_gemm(const int* __restrict__ nidx_g,
                    const float* __restrict__ feat,
                    const float* __restrict__ Wm,
                    const float* __restrict__ bias,
                    float* __restrict__ out) {
  const int tid  = threadIdx.x;
  const int lane = tid & 63;
  const int wid  = tid >> 6;
  const int wr   = wid >> 1;
  const int wc   = wid & 1;
  const int n0   = blockIdx.x * BN;
  const int mb   = blockIdx.y;

  __shared__ __align__(16) unsigned short As[BM * 64];
  __shared__ __align__(16) unsigned short Bs[BM * 64];
  __shared__ int nid[BM];

  if (tid < BM) nid[tid] = nidx_g[mb * BM + tid];
  __syncthreads();

  const int lr = tid >> 4;
  const int lc = tid & 15;

  const float* aptr[8];
  const float* wptr[8];
#pragma unroll
  for (int p = 0; p < 8; ++p) {
    int row = p * 16 + lr;
    aptr[p] = feat + (size_t)nid[row] * D_IN + lc * 4;
    wptr[p] = Wm + (size_t)(n0 + row) * D_IN + lc * 4;
  }

  f32x4 acc[4][4];
#pragma unroll
  for (int i = 0; i < 4; ++i)
#pragma unroll
    for (int j = 0; j < 4; ++j)
      acc[i][j] = (f32x4){0.f, 0.f, 0.f, 0.f};

  const int frow = lane & 15;
  const int kcb  = (lane >> 4) * 16;
  const int arow = wr * 64 + frow;
  const int brow = wc * 64 + frow;

  for (int k0 = 0; k0 < D_IN; k0 += 64) {
    __syncthreads();
#pragma unroll
    for (int p = 0; p < 8; ++p) {
      int row = p * 16 + lr;
      f32x4 av = *(const f32x4*)(aptr[p] + k0);
      f32x4 wv = *(const f32x4*)(wptr[p] + k0);
      us4 a4, w4;
      a4.x = f2bf(av.x); a4.y = f2bf(av.y); a4.z = f2bf(av.z); a4.w = f2bf(av.w);
      w4.x = f2bf(wv.x); w4.y = f2bf(wv.y); w4.z = f2bf(wv.z); w4.w = f2bf(wv.w);
      *(us4*)((char*)As + swz(row, lc * 8)) = a4;
      *(us4*)((char*)Bs + swz(row, lc * 8)) = w4;
    }
    __syncthreads();

#pragma unroll
    for (int kk = 0; kk < 2; ++kk) {
      short8 af[4], bfr[4];
#pragma unroll
      for (int mi = 0; mi < 4; ++mi)
        af[mi] = *(const short8*)((const char*)As + swz(arow + mi * 16, kk * 64 + kcb));
#pragma unroll
      for (int ni = 0; ni < 4; ++ni)
        bfr[ni] = *(const short8*)((const char*)Bs + swz(brow + ni * 16, kk * 64 + kcb));
#pragma unroll
      for (int mi = 0; mi < 4; ++mi)
#pragma unroll
        for (int ni = 0; ni < 4; ++ni)
          acc[mi][ni] = __builtin_amdgcn_mfma_f32_16x16x32_bf16(af[mi], bfr[ni], acc[mi][ni], 0, 0, 0);
    }
  }

  const int rq = lane >> 4;
#pragma unroll
  for (int ni = 0; ni < 4; ++ni) {
    int col = n0 + wc * 64 + ni * 16 + frow;
    float bv = bias[col];
#pragma unroll
    for (int bl = 0; bl < 2; ++bl) {
      float s = 0.f;
#pragma unroll
      for (int m2 = 0; m2 < 2; ++m2) {
        int mi = bl * 2 + m2;
#pragma unroll
        for (int r = 0; r < 4; ++r)
          s += fmaxf(acc[mi][ni][r] + bv, 0.f);
      }
      s += __shfl_xor(s, 16);
      s += __shfl_xor(s, 32);
      if (rq == 0) {
        int bb = mb * 4 + wr * 2 + bl;
        out[(size_t)bb * D_H + col] = s * (1.0f / (float)S_NB);
      }
    }
  }
}

extern "C" void kernel_launch(void* const* d_in, const int* in_sizes, int n_in,
                              void* d_out, int out_size, void* d_ws, size_t ws_size,
                              hipStream_t stream) {
  const int*   nidx = (const int*)d_in[0];    // [10000,32]
  const float* feat = (const float*)d_in[1];  // [100000,512]
  const float* Wm   = (const float*)d_in[2];  // [512,512]
  const float* bias = (const float*)d_in[3];  // [512]
  float* out = (float*)d_out;                 // [10000,512]

  const size_t wb_elems = (size_t)D_H * D_IN;                           // 262144
  const size_t wb_bytes = wb_elems * sizeof(unsigned short);            // 0.5 MB
  const size_t h_bytes  = (size_t)NNODE * D_H * sizeof(unsigned short); // 102.4 MB

  if (ws_size >= wb_bytes + h_bytes) {
    unsigned short* Wb = (unsigned short*)d_ws;
    unsigned short* Hb = Wb + wb_elems;
    cvt_bf16<<<128, 256, 0, stream>>>(Wm, Wb, D_H * D_IN / 8);
    gemm_f32c<<<NTILES, 256, 0, stream>>>(feat, Wb, bias, Hb);
    pool_mean4<<<NBATCH / 4, 256, 0, stream>>>(Hb, nidx, out);
  } else if (ws_size >= h_bytes) {
    unsigned short* Hb = (unsigned short*)d_ws;
    dim3 g1(D_H / BN, (NNODE + BM - 1) / BM);
    gemm_h<<<g1, 256, 0, stream>>>(feat, Wm, bias, Hb);
    pool_mean4<<<NBATCH / 4, 256, 0, stream>>>(Hb, nidx, out);
  } else {
    dim3 grid(D_H / BN, NBATCH / 4);
    pool_aggr_gemm<<<grid, 256, 0, stream>>>(nidx, feat, Wm, bias, out);
  }
}